// Round 8
// baseline (426.882 us; speedup 1.0000x reference)
//
#include <hip/hip_runtime.h>
#include <hip/hip_bf16.h>

// Problem constants: B=4, N=1024, C=1152, H=16, hd=72
#define PB 4
#define PN 1024
#define PC 1152
#define PH 16
#define PHD 72
#define BH 64
#define QKV_COLS 3456
#define OUT_ELEMS ((size_t)PB*PN*PC)   // 4718592
#define K_DIM 1152

// Blocked f16 layouts (per (bh, 64-row chunk), 6144 halves = 12288 B):
//  q/k:  [dq(12)][row(64)][8]   element (n,d) -> (d>>3)*512 + (n&63)*8 + (d&7)
//  vt :  [kq(8)][hd(96)][8]     element (n,d) -> ((n&63)>>3)*768 + d*8 + (n&7)
#define CHUNK_HALVES 6144
#define HEAD_HALVES (16*CHUNK_HALVES)       // 98304
#define BUF_HALVES ((size_t)BH*HEAD_HALVES) // 6291456 per buffer

typedef _Float16 half8_t __attribute__((ext_vector_type(8)));
typedef _Float16 half4_t __attribute__((ext_vector_type(4)));
typedef float float4v __attribute__((ext_vector_type(4)));

// q pre-scale: hd^-0.5 * log2(e)  (softmax computed base-2, exactly equivalent)
#define QSCALE (0.11785113019775792f * 1.4426950408889634f)

__device__ __forceinline__ void load16_lds(const _Float16* g, _Float16* l) {
    __builtin_amdgcn_global_load_lds(
        (const __attribute__((address_space(1))) void*)g,
        (__attribute__((address_space(3))) void*)l, 16, 0, 0);
}

// ---------------------------------------------------------------------------
// Fused prep: f32->f16 for x / qkv_w / proj_w, q-pad zeroing, enc k/v
// conversion to blocked layouts. One launch, blockIdx-range dispatch.
//   [0,2304)            x conversion        (589824 half8)
//   [2304,4248)         qkv_w conversion    (497664 half8)
//   [4248,4896)         proj_w conversion   (165888 half8)
//   [4896,5664)         q-pad zero          (196608 half8)
//   [5664,6688)         enc convert         (1024 chunk-blocks)
// ---------------------------------------------------------------------------
__device__ __forceinline__ void cvt8(const float* __restrict__ in,
                                     _Float16* __restrict__ out, int i)
{
    float4 a = ((const float4*)in)[2 * i];
    float4 b = ((const float4*)in)[2 * i + 1];
    half8_t h;
    h[0] = (_Float16)a.x; h[1] = (_Float16)a.y; h[2] = (_Float16)a.z; h[3] = (_Float16)a.w;
    h[4] = (_Float16)b.x; h[5] = (_Float16)b.y; h[6] = (_Float16)b.z; h[7] = (_Float16)b.w;
    ((half8_t*)out)[i] = h;
}

__global__ __launch_bounds__(256) void prep(
    const float* __restrict__ x, const float* __restrict__ qkv_w,
    const float* __restrict__ proj_w,
    const float* __restrict__ ek, const float* __restrict__ ev,
    _Float16* __restrict__ x_h, _Float16* __restrict__ qkvw_h,
    _Float16* __restrict__ projw_h, _Float16* __restrict__ qh,
    _Float16* __restrict__ ekh, _Float16* __restrict__ evth)
{
    const int b = blockIdx.x, t = threadIdx.x;
    if (b < 2304) {
        cvt8(x, x_h, b * 256 + t);
    } else if (b < 4248) {
        cvt8(qkv_w, qkvw_h, (b - 2304) * 256 + t);
    } else if (b < 4896) {
        cvt8(proj_w, projw_h, (b - 4248) * 256 + t);
    } else if (b < 5664) {
        int i = (b - 4896) * 256 + t;
        int chunk = i / 192, within = i - chunk * 192;
        half8_t z = {};
        *(half8_t*)(qh + (size_t)chunk * CHUNK_HALVES + 4608 + within * 8) = z;
    } else {
        int bid = b - 5664;
        int bh = bid >> 4, nblk = bid & 15;
        const float* ksrc = ek + ((size_t)bh * PN + nblk * 64) * PHD;
        const float* vsrc = ev + ((size_t)bh * PN + nblk * 64) * PHD;
        _Float16* kdst = ekh  + ((size_t)bh * 16 + nblk) * CHUNK_HALVES;
        _Float16* vdst = evth + ((size_t)bh * 16 + nblk) * CHUNK_HALVES;
        for (int i = t; i < 64 * 18; i += 256) {
            int n = i / 18, d4 = (i % 18) * 4;
            float4 kv = *(const float4*)&ksrc[n * PHD + d4];
            float4 vv = *(const float4*)&vsrc[n * PHD + d4];
            float ka[4] = {kv.x, kv.y, kv.z, kv.w};
            float va[4] = {vv.x, vv.y, vv.z, vv.w};
#pragma unroll
            for (int kk = 0; kk < 4; ++kk) {
                int d = d4 + kk;
                kdst[(d >> 3) * 512 + n * 8 + (d & 7)] = (_Float16)ka[kk];
                vdst[(n >> 3) * 768 + d * 8 + (n & 7)] = (_Float16)va[kk];
            }
        }
    }
}

// ---------------------------------------------------------------------------
// MFMA f16 GEMM, 128x128 tile, BK=64, grouped-swizzle 1D grid.
// Orientation: q/k tiles (c0 < 2*PC) and proj use C^T (operand swap) so each
// lane owns 4 consecutive cols -> vectorized stores. v tiles use normal C.
// MODE 0: QKV epilogue -> blocked f16 q/k/vt (q pre-scaled by QSCALE)
// MODE 1: proj epilogue -> f32 (M,C) + bias, float4 stores
// ---------------------------------------------------------------------------
template<int MODE>
__global__ __launch_bounds__(256) void gemm_mfma(
    const _Float16* __restrict__ A, const _Float16* __restrict__ Bm,
    const float* __restrict__ bias,
    _Float16* __restrict__ qh, _Float16* __restrict__ kh,
    _Float16* __restrict__ vth, float* __restrict__ out, int c_tiles)
{
    const int t    = threadIdx.x;
    const int lane = t & 63;
    const int w    = t >> 6;
    const int wm   = w >> 1, wn = w & 1;
    const int lrow = lane & 15, quad = lane >> 4;

    const int per_group = c_tiles * 8;
    const int g  = blockIdx.x / per_group;
    const int r_ = blockIdx.x - g * per_group;
    const int m0 = (g * 8 + (r_ & 7)) * 128;
    const int c0 = (r_ >> 3) * 128;

    const bool tr = (MODE == 1) || (c0 < 2 * PC);   // q/k + proj transposed

    __shared__ _Float16 As[8192];
    __shared__ _Float16 Bs[8192];

    int rowS[4], koff[4], ldsOff[4];
#pragma unroll
    for (int i = 0; i < 4; ++i) {
        int idx = w * 256 + i * 64 + lane;
        int kt2 = idx >> 9, qq = (idx >> 7) & 3;
        rowS[i]   = idx & 127;
        koff[i]   = kt2 * 32 + qq * 8;
        ldsOff[i] = idx * 8;
    }

    const _Float16* aBase = A  + (size_t)m0 * K_DIM;
    const _Float16* bBase = Bm + (size_t)c0 * K_DIM;

    float4v acc[4][4];
#pragma unroll
    for (int ti = 0; ti < 4; ++ti)
#pragma unroll
        for (int tj = 0; tj < 4; ++tj)
            acc[ti][tj] = (float4v){0.f, 0.f, 0.f, 0.f};

    for (int kb = 0; kb < K_DIM; kb += 64) {
        __syncthreads();
#pragma unroll
        for (int i = 0; i < 4; ++i) {
            load16_lds(aBase + (size_t)rowS[i] * K_DIM + kb + koff[i], &As[ldsOff[i]]);
            load16_lds(bBase + (size_t)rowS[i] * K_DIM + kb + koff[i], &Bs[ldsOff[i]]);
        }
        __syncthreads();
#pragma unroll
        for (int s = 0; s < 2; ++s) {
            half8_t af[4], bf[4];
#pragma unroll
            for (int ti = 0; ti < 4; ++ti)
                af[ti] = *(const half8_t*)&As[(((s * 4 + quad) * 128) + wm * 64 + ti * 16 + lrow) * 8];
#pragma unroll
            for (int tj = 0; tj < 4; ++tj)
                bf[tj] = *(const half8_t*)&Bs[(((s * 4 + quad) * 128) + wn * 64 + tj * 16 + lrow) * 8];
            if (tr) {
#pragma unroll
                for (int ti = 0; ti < 4; ++ti)
#pragma unroll
                    for (int tj = 0; tj < 4; ++tj)
                        acc[ti][tj] = __builtin_amdgcn_mfma_f32_16x16x32_f16(
                            bf[tj], af[ti], acc[ti][tj], 0, 0, 0);
            } else {
#pragma unroll
                for (int ti = 0; ti < 4; ++ti)
#pragma unroll
                    for (int tj = 0; tj < 4; ++tj)
                        acc[ti][tj] = __builtin_amdgcn_mfma_f32_16x16x32_f16(
                            af[ti], bf[tj], acc[ti][tj], 0, 0, 0);
            }
        }
    }

    if (MODE == 1) {
#pragma unroll
        for (int tj = 0; tj < 4; ++tj) {
            int cg = c0 + wn * 64 + tj * 16 + quad * 4;
            float4v bv = *(const float4v*)&bias[cg];
#pragma unroll
            for (int ti = 0; ti < 4; ++ti) {
                int m = m0 + wm * 64 + ti * 16 + lrow;
                float4v o;
#pragma unroll
                for (int r = 0; r < 4; ++r) o[r] = acc[ti][tj][r] + bv[r];
                *(float4v*)&out[(size_t)m * PC + cg] = o;
            }
        }
    } else if (tr) {
        const int jq = c0 / PC;               // 0 = q, 1 = k (uniform per block)
        const float mulv = (jq == 0) ? QSCALE : 1.f;
        _Float16* dstp = (jq == 0) ? qh : kh;
#pragma unroll
        for (int tj = 0; tj < 4; ++tj) {
            int cg  = c0 + wn * 64 + tj * 16 + quad * 4;
            int rem = cg - jq * PC;
            int h   = rem / PHD;
            int ds  = rem - h * PHD;          // multiple of 4
            float4v bv = *(const float4v*)&bias[cg];
#pragma unroll
            for (int ti = 0; ti < 4; ++ti) {
                int m = m0 + wm * 64 + ti * 16 + lrow;
                int b = m >> 10, n = m & 1023;
                size_t chunk = ((size_t)(b * PH + h) * 16 + (n >> 6)) * CHUNK_HALVES;
                half4_t hv;
#pragma unroll
                for (int r = 0; r < 4; ++r)
                    hv[r] = (_Float16)((acc[ti][tj][r] + bv[r]) * mulv);
                *(half4_t*)&dstp[chunk + (ds >> 3) * 512 + (n & 63) * 8 + (ds & 7)] = hv;
            }
        }
    } else {
#pragma unroll
        for (int tj = 0; tj < 4; ++tj) {
            int c   = c0 + wn * 64 + tj * 16 + lrow;
            int rem = c - 2 * PC;
            int h   = rem / PHD;
            int d   = rem - h * PHD;
            float bv = bias[c];
#pragma unroll
            for (int ti = 0; ti < 4; ++ti) {
                int mg = m0 + wm * 64 + ti * 16 + quad * 4;
                int b = mg >> 10, n = mg & 1023;
                size_t chunk = ((size_t)(b * PH + h) * 16 + (n >> 6)) * CHUNK_HALVES;
                half4_t hv;
#pragma unroll
                for (int r = 0; r < 4; ++r)
                    hv[r] = (_Float16)(acc[ti][tj][r] + bv);
                *(half4_t*)&vth[chunk + ((n & 63) >> 3) * 768 + d * 8 + (n & 7)] = hv;
            }
        }
    }
}

// ---------------------------------------------------------------------------
// One dual-strip transposed flash-attention step (base-2 softmax).
// Each wave handles 2 Q-strips (32 rows); every K/V fragment read feeds
// 2 MFMAs, halving LDS-pipe traffic per unit work vs 1-strip.
// ---------------------------------------------------------------------------
__device__ __forceinline__ void attn_step2(
    const half8_t qf[2][3], const _Float16* Ks, const _Float16* Vts,
    _Float16* P0, _Float16* P1,
    float4v O0[5], float4v O1[5], float m_run[2], float l_run[2],
    int ln, int quad)
{
    float4v accS[2][4];
#pragma unroll
    for (int s = 0; s < 2; ++s)
#pragma unroll
        for (int ct = 0; ct < 4; ++ct) accS[s][ct] = (float4v){0.f, 0.f, 0.f, 0.f};
#pragma unroll
    for (int ks = 0; ks < 3; ++ks) {
#pragma unroll
        for (int ct = 0; ct < 4; ++ct) {
            half8_t kf = *(const half8_t*)&Ks[(((ks * 4 + quad) * 64) + ct * 16 + ln) * 8];
            accS[0][ct] = __builtin_amdgcn_mfma_f32_16x16x32_f16(kf, qf[0][ks], accS[0][ct], 0, 0, 0);
            accS[1][ct] = __builtin_amdgcn_mfma_f32_16x16x32_f16(kf, qf[1][ks], accS[1][ct], 0, 0, 0);
        }
    }

    const int pbase = (quad >> 1) * 128 + ln * 8 + (quad & 1) * 4;
#pragma unroll
    for (int s = 0; s < 2; ++s) {
        _Float16* Pr = s ? P1 : P0;
        float mx = -1e30f;
#pragma unroll
        for (int ct = 0; ct < 4; ++ct)
#pragma unroll
            for (int r = 0; r < 4; ++r) mx = fmaxf(mx, accS[s][ct][r]);
        mx = fmaxf(mx, __shfl_xor(mx, 16));
        mx = fmaxf(mx, __shfl_xor(mx, 32));
        float m_new = fmaxf(m_run[s], mx);
        float alpha = exp2f(m_run[s] - m_new);
        m_run[s] = m_new;

        float lsum = 0.f;
#pragma unroll
        for (int ct = 0; ct < 4; ++ct) {
            half4_t pk;
#pragma unroll
            for (int r = 0; r < 4; ++r) {
                float p = exp2f(accS[s][ct][r] - m_new);
                lsum += p;
                pk[r] = (_Float16)p;
            }
            *(half4_t*)&Pr[pbase + ct * 256] = pk;
        }
        lsum += __shfl_xor(lsum, 16);
        lsum += __shfl_xor(lsum, 32);
        l_run[s] = l_run[s] * alpha + lsum;

        float4v* O = s ? O1 : O0;
#pragma unroll
        for (int ct = 0; ct < 5; ++ct) O[ct] *= alpha;
    }

#pragma unroll
    for (int ks = 0; ks < 2; ++ks) {
        half8_t pf0 = *(const half8_t*)&P0[(ks * 4 + quad) * 128 + ln * 8];
        half8_t pf1 = *(const half8_t*)&P1[(ks * 4 + quad) * 128 + ln * 8];
#pragma unroll
        for (int ct = 0; ct < 5; ++ct) {
            half8_t vf = *(const half8_t*)&Vts[(((ks * 4 + quad) * 96) + ct * 16 + ln) * 8];
            O0[ct] = __builtin_amdgcn_mfma_f32_16x16x32_f16(vf, pf0, O0[ct], 0, 0, 0);
            O1[ct] = __builtin_amdgcn_mfma_f32_16x16x32_f16(vf, pf1, O1[ct], 0, 0, 0);
        }
    }
}

// ---------------------------------------------------------------------------
// Fused dual-pass flash attention. 128 threads = 2 waves x 2 strips x 16 rows.
// Single K/V buffer (~32.5 KB LDS -> 4 blocks/CU); Q in registers; own pass
// then enc pass; loss in fp32 registers. XCD-affinity swizzle.
// ---------------------------------------------------------------------------
__global__ __launch_bounds__(128) void attn_fused(
    const _Float16* __restrict__ qh, const _Float16* __restrict__ kh,
    const _Float16* __restrict__ vth,
    const _Float16* __restrict__ ekh, const _Float16* __restrict__ evth,
    _Float16* __restrict__ xouth, float* __restrict__ loss_out)
{
    const int t = threadIdx.x;
    const int lane = t & 63;
    const int w = t >> 6;                    // 0..1
    const int ln = lane & 15;
    const int quad = lane >> 4;

    const int lid  = blockIdx.x;             // 1024 blocks
    const int bh   = (lid & 7) * 8 + ((lid >> 3) >> 4);
    const int nblk = (lid >> 3) & 15;

    __shared__ _Float16 Ks[CHUNK_HALVES];
    __shared__ _Float16 Vs[CHUNK_HALVES];
    __shared__ _Float16 Ps[4096];            // 2 waves x 2 strips x 1024
    __shared__ float red[128];

    _Float16* P0 = Ps + w * 2048;
    _Float16* P1 = P0 + 1024;

    // Q fragments straight to registers (strip s rows: w*32 + s*16 + ln)
    const _Float16* qc = qh + ((size_t)bh * 16 + nblk) * CHUNK_HALVES;
    half8_t qf[2][3];
#pragma unroll
    for (int s = 0; s < 2; ++s)
#pragma unroll
        for (int ks = 0; ks < 3; ++ks)
            qf[s][ks] = *(const half8_t*)&qc[(((ks * 4 + quad) * 64) + w * 32 + s * 16 + ln) * 8];

    const _Float16* kbo = kh   + (size_t)bh * HEAD_HALVES;
    const _Float16* vbo = vth  + (size_t)bh * HEAD_HALVES;
    const _Float16* kbe = ekh  + (size_t)bh * HEAD_HALVES;
    const _Float16* vbe = evth + (size_t)bh * HEAD_HALVES;

    float4v Oo0[5], Oo1[5], Oe0[5], Oe1[5];
#pragma unroll
    for (int ct = 0; ct < 5; ++ct) {
        Oo0[ct] = (float4v){0.f, 0.f, 0.f, 0.f};
        Oo1[ct] = (float4v){0.f, 0.f, 0.f, 0.f};
        Oe0[ct] = (float4v){0.f, 0.f, 0.f, 0.f};
        Oe1[ct] = (float4v){0.f, 0.f, 0.f, 0.f};
    }
    float m_o[2] = {-1e30f, -1e30f}, l_o[2] = {0.f, 0.f};
    float m_e[2] = {-1e30f, -1e30f}, l_e[2] = {0.f, 0.f};

    // pass 0: own K/V
    for (int kt = 0; kt < 16; ++kt) {
        const _Float16* kc = kbo + (size_t)kt * CHUNK_HALVES;
        const _Float16* vc = vbo + (size_t)kt * CHUNK_HALVES;
        __syncthreads();
#pragma unroll
        for (int i = 0; i < 6; ++i) {
            int u = i * 128 + t;
            load16_lds(kc + u * 8, &Ks[u * 8]);
            load16_lds(vc + u * 8, &Vs[u * 8]);
        }
        __syncthreads();
        attn_step2(qf, Ks, Vs, P0, P1, Oo0, Oo1, m_o, l_o, ln, quad);
    }
    // pass 1: encoder K/V
    for (int kt = 0; kt < 16; ++kt) {
        const _Float16* kc = kbe + (size_t)kt * CHUNK_HALVES;
        const _Float16* vc = vbe + (size_t)kt * CHUNK_HALVES;
        __syncthreads();
#pragma unroll
        for (int i = 0; i < 6; ++i) {
            int u = i * 128 + t;
            load16_lds(kc + u * 8, &Ks[u * 8]);
            load16_lds(vc + u * 8, &Vs[u * 8]);
        }
        __syncthreads();
        attn_step2(qf, Ks, Vs, P0, P1, Oe0, Oe1, m_e, l_e, ln, quad);
    }

    const int b = bh >> 4, h = bh & 15;
    float lacc = 0.f;
#pragma unroll
    for (int s = 0; s < 2; ++s) {
        const float4v* Oo = s ? Oo1 : Oo0;
        const float4v* Oe = s ? Oe1 : Oe0;
        const float inv_o = 1.0f / l_o[s];
        const float inv_e = 1.0f / l_e[s];
        const int nrow = nblk * 64 + w * 32 + s * 16 + ln;
        const size_t rowbase = (size_t)(b * PN + nrow) * PC + h * PHD;
#pragma unroll
        for (int ct = 0; ct < 5; ++ct) {
            int d0 = ct * 16 + quad * 4;
            if (d0 < PHD) {                  // ct=4: only quads 0,1 valid
                half4_t oh;
#pragma unroll
                for (int r = 0; r < 4; ++r) {
                    float own = Oo[ct][r] * inv_o;
                    oh[r] = (_Float16)own;
                    float df = own - Oe[ct][r] * inv_e;
                    lacc += df * df;
                }
                *(half4_t*)&xouth[rowbase + d0] = oh;   // 8B aligned
            }
        }
    }

    red[t] = lacc;
    __syncthreads();
    for (int off = 64; off > 0; off >>= 1) {
        if (t < off) red[t] += red[t + off];
        __syncthreads();
    }
    if (t == 0) atomicAdd(loss_out, red[0] * (1.0f / (float)OUT_ELEMS));
}

// ---------------------------------------------------------------------------
extern "C" void kernel_launch(void* const* d_in, const int* in_sizes, int n_in,
                              void* d_out, int out_size, void* d_ws, size_t ws_size,
                              hipStream_t stream)
{
    const float* x      = (const float*)d_in[0];
    const float* enc_k  = (const float*)d_in[1];
    const float* enc_v  = (const float*)d_in[2];
    const float* qkv_w  = (const float*)d_in[3];
    const float* qkv_b  = (const float*)d_in[4];
    const float* proj_w = (const float*)d_in[5];
    const float* proj_b = (const float*)d_in[6];

    float* out = (float*)d_out;

    _Float16* x_h     = (_Float16*)d_ws;
    _Float16* qkvw_h  = x_h + OUT_ELEMS;
    _Float16* projw_h = qkvw_h + (size_t)QKV_COLS * PC;
    _Float16* xout_h  = projw_h + (size_t)PC * PC;
    _Float16* q_h     = xout_h + OUT_ELEMS;
    _Float16* k_h     = q_h  + BUF_HALVES;
    _Float16* vt_h    = k_h  + BUF_HALVES;
    _Float16* ek_h    = vt_h + BUF_HALVES;
    _Float16* evt_h   = ek_h + BUF_HALVES;

    // 0. zero loss slot
    hipMemsetAsync(out + OUT_ELEMS, 0, sizeof(float), stream);

    // 1. fused prep (conversions + q-pad zero + enc convert)
    prep<<<6688, 256, 0, stream>>>(x, qkv_w, proj_w, enc_k, enc_v,
                                   x_h, qkvw_h, projw_h, q_h, ek_h, evt_h);

    // 2. QKV projection -> blocked f16 q/k/vt (q pre-scaled by QSCALE)
    gemm_mfma<0><<<(QKV_COLS / 128) * ((PB * PN) / 128), 256, 0, stream>>>(
        x_h, qkvw_h, qkv_b, q_h, k_h, vt_h, nullptr, QKV_COLS / 128);

    // 3. Fused own+enc attention -> xout_h + loss into out[OUT_ELEMS]
    attn_fused<<<16 * BH, 128, 0, stream>>>(
        q_h, k_h, vt_h, ek_h, evt_h, xout_h, out + OUT_ELEMS);

    // 4. Output projection (transposed, float4 stores)
    gemm_mfma<1><<<(PC / 128) * ((PB * PN) / 128), 256, 0, stream>>>(
        xout_h, projw_h, proj_b, nullptr, nullptr, nullptr, out, PC / 128);
}

// Round 9
// 375.446 us; speedup vs baseline: 1.1370x; 1.1370x over previous
//
#include <hip/hip_runtime.h>
#include <hip/hip_bf16.h>

// Problem constants: B=4, N=1024, C=1152, H=16, hd=72
#define PB 4
#define PN 1024
#define PC 1152
#define PH 16
#define PHD 72
#define BH 64
#define QKV_COLS 3456
#define OUT_ELEMS ((size_t)PB*PN*PC)   // 4718592
#define K_DIM 1152

// Blocked f16 layouts (per (bh, 64-row chunk), 6144 halves = 12288 B):
//  q:   [dq(12)][row(64)][8]            (n,d) -> (d>>3)*512 + (n&63)*8 + (d&7)
//  k:   [sub(2)][dq(12)][row(32)][8]    (n,d) -> ((n&63)>>5)*3072 + (d>>3)*256 + (n&31)*8 + (d&7)
//  vt:  [kq(8)][hd(96)][8]              (n,d) -> ((n&63)>>3)*768 + d*8 + (n&7)
// k and vt are both contiguous per 32-row sub-chunk (3072 halves = 6 KB).
#define CHUNK_HALVES 6144
#define SUB_HALVES 3072
#define HEAD_HALVES (16*CHUNK_HALVES)       // 98304
#define BUF_HALVES ((size_t)BH*HEAD_HALVES) // 6291456 per buffer

typedef _Float16 half8_t __attribute__((ext_vector_type(8)));
typedef _Float16 half4_t __attribute__((ext_vector_type(4)));
typedef float float4v __attribute__((ext_vector_type(4)));

// q pre-scale: hd^-0.5 * log2(e)  (softmax computed base-2, exactly equivalent)
#define QSCALE (0.11785113019775792f * 1.4426950408889634f)

__device__ __forceinline__ void load16_lds(const _Float16* g, _Float16* l) {
    __builtin_amdgcn_global_load_lds(
        (const __attribute__((address_space(1))) void*)g,
        (__attribute__((address_space(3))) void*)l, 16, 0, 0);
}

// ---------------------------------------------------------------------------
// Fused prep: f32->f16 for x / qkv_w / proj_w, q-pad zeroing, enc k/v
// conversion to blocked layouts. One launch, blockIdx-range dispatch.
// ---------------------------------------------------------------------------
__device__ __forceinline__ void cvt8(const float* __restrict__ in,
                                     _Float16* __restrict__ out, int i)
{
    float4 a = ((const float4*)in)[2 * i];
    float4 b = ((const float4*)in)[2 * i + 1];
    half8_t h;
    h[0] = (_Float16)a.x; h[1] = (_Float16)a.y; h[2] = (_Float16)a.z; h[3] = (_Float16)a.w;
    h[4] = (_Float16)b.x; h[5] = (_Float16)b.y; h[6] = (_Float16)b.z; h[7] = (_Float16)b.w;
    ((half8_t*)out)[i] = h;
}

__global__ __launch_bounds__(256) void prep(
    const float* __restrict__ x, const float* __restrict__ qkv_w,
    const float* __restrict__ proj_w,
    const float* __restrict__ ek, const float* __restrict__ ev,
    _Float16* __restrict__ x_h, _Float16* __restrict__ qkvw_h,
    _Float16* __restrict__ projw_h, _Float16* __restrict__ qh,
    _Float16* __restrict__ ekh, _Float16* __restrict__ evth)
{
    const int b = blockIdx.x, t = threadIdx.x;
    if (b < 2304) {
        cvt8(x, x_h, b * 256 + t);
    } else if (b < 4248) {
        cvt8(qkv_w, qkvw_h, (b - 2304) * 256 + t);
    } else if (b < 4896) {
        cvt8(proj_w, projw_h, (b - 4248) * 256 + t);
    } else if (b < 5664) {
        int i = (b - 4896) * 256 + t;
        int chunk = i / 192, within = i - chunk * 192;
        half8_t z = {};
        *(half8_t*)(qh + (size_t)chunk * CHUNK_HALVES + 4608 + within * 8) = z;
    } else {
        int bid = b - 5664;
        int bh = bid >> 4, nblk = bid & 15;
        const float* ksrc = ek + ((size_t)bh * PN + nblk * 64) * PHD;
        const float* vsrc = ev + ((size_t)bh * PN + nblk * 64) * PHD;
        _Float16* kdst = ekh  + ((size_t)bh * 16 + nblk) * CHUNK_HALVES;
        _Float16* vdst = evth + ((size_t)bh * 16 + nblk) * CHUNK_HALVES;
        for (int i = t; i < 64 * 18; i += 256) {
            int n = i / 18, d4 = (i % 18) * 4;
            float4 kv = *(const float4*)&ksrc[n * PHD + d4];
            float4 vv = *(const float4*)&vsrc[n * PHD + d4];
            float ka[4] = {kv.x, kv.y, kv.z, kv.w};
            float va[4] = {vv.x, vv.y, vv.z, vv.w};
#pragma unroll
            for (int kk = 0; kk < 4; ++kk) {
                int d = d4 + kk;
                kdst[(n >> 5) * SUB_HALVES + (d >> 3) * 256 + (n & 31) * 8 + (d & 7)] = (_Float16)ka[kk];
                vdst[(n >> 3) * 768 + d * 8 + (n & 7)] = (_Float16)va[kk];
            }
        }
    }
}

// ---------------------------------------------------------------------------
// MFMA f16 GEMM, 128x128 tile, BK=64, grouped-swizzle 1D grid.
// Orientation: q/k tiles (c0 < 2*PC) and proj use C^T (operand swap) so each
// lane owns 4 consecutive cols -> vectorized stores. v tiles use normal C.
// MODE 0: QKV epilogue -> blocked f16 q/k/vt (q pre-scaled by QSCALE)
// MODE 1: proj epilogue -> f32 (M,C) + bias, float4 stores
// ---------------------------------------------------------------------------
template<int MODE>
__global__ __launch_bounds__(256) void gemm_mfma(
    const _Float16* __restrict__ A, const _Float16* __restrict__ Bm,
    const float* __restrict__ bias,
    _Float16* __restrict__ qh, _Float16* __restrict__ kh,
    _Float16* __restrict__ vth, float* __restrict__ out, int c_tiles)
{
    const int t    = threadIdx.x;
    const int lane = t & 63;
    const int w    = t >> 6;
    const int wm   = w >> 1, wn = w & 1;
    const int lrow = lane & 15, quad = lane >> 4;

    const int per_group = c_tiles * 8;
    const int g  = blockIdx.x / per_group;
    const int r_ = blockIdx.x - g * per_group;
    const int m0 = (g * 8 + (r_ & 7)) * 128;
    const int c0 = (r_ >> 3) * 128;

    const bool tr = (MODE == 1) || (c0 < 2 * PC);   // q/k + proj transposed

    __shared__ _Float16 As[8192];
    __shared__ _Float16 Bs[8192];

    int rowS[4], koff[4], ldsOff[4];
#pragma unroll
    for (int i = 0; i < 4; ++i) {
        int idx = w * 256 + i * 64 + lane;
        int kt2 = idx >> 9, qq = (idx >> 7) & 3;
        rowS[i]   = idx & 127;
        koff[i]   = kt2 * 32 + qq * 8;
        ldsOff[i] = idx * 8;
    }

    const _Float16* aBase = A  + (size_t)m0 * K_DIM;
    const _Float16* bBase = Bm + (size_t)c0 * K_DIM;

    float4v acc[4][4];
#pragma unroll
    for (int ti = 0; ti < 4; ++ti)
#pragma unroll
        for (int tj = 0; tj < 4; ++tj)
            acc[ti][tj] = (float4v){0.f, 0.f, 0.f, 0.f};

    for (int kb = 0; kb < K_DIM; kb += 64) {
        __syncthreads();
#pragma unroll
        for (int i = 0; i < 4; ++i) {
            load16_lds(aBase + (size_t)rowS[i] * K_DIM + kb + koff[i], &As[ldsOff[i]]);
            load16_lds(bBase + (size_t)rowS[i] * K_DIM + kb + koff[i], &Bs[ldsOff[i]]);
        }
        __syncthreads();
#pragma unroll
        for (int s = 0; s < 2; ++s) {
            half8_t af[4], bf[4];
#pragma unroll
            for (int ti = 0; ti < 4; ++ti)
                af[ti] = *(const half8_t*)&As[(((s * 4 + quad) * 128) + wm * 64 + ti * 16 + lrow) * 8];
#pragma unroll
            for (int tj = 0; tj < 4; ++tj)
                bf[tj] = *(const half8_t*)&Bs[(((s * 4 + quad) * 128) + wn * 64 + tj * 16 + lrow) * 8];
            if (tr) {
#pragma unroll
                for (int ti = 0; ti < 4; ++ti)
#pragma unroll
                    for (int tj = 0; tj < 4; ++tj)
                        acc[ti][tj] = __builtin_amdgcn_mfma_f32_16x16x32_f16(
                            bf[tj], af[ti], acc[ti][tj], 0, 0, 0);
            } else {
#pragma unroll
                for (int ti = 0; ti < 4; ++ti)
#pragma unroll
                    for (int tj = 0; tj < 4; ++tj)
                        acc[ti][tj] = __builtin_amdgcn_mfma_f32_16x16x32_f16(
                            af[ti], bf[tj], acc[ti][tj], 0, 0, 0);
            }
        }
    }

    if (MODE == 1) {
#pragma unroll
        for (int tj = 0; tj < 4; ++tj) {
            int cg = c0 + wn * 64 + tj * 16 + quad * 4;
            float4v bv = *(const float4v*)&bias[cg];
#pragma unroll
            for (int ti = 0; ti < 4; ++ti) {
                int m = m0 + wm * 64 + ti * 16 + lrow;
                float4v o;
#pragma unroll
                for (int r = 0; r < 4; ++r) o[r] = acc[ti][tj][r] + bv[r];
                *(float4v*)&out[(size_t)m * PC + cg] = o;
            }
        }
    } else if (tr) {
        const int jq = c0 / PC;               // 0 = q, 1 = k (uniform per block)
        const float mulv = (jq == 0) ? QSCALE : 1.f;
        _Float16* dstp = (jq == 0) ? qh : kh;
#pragma unroll
        for (int tj = 0; tj < 4; ++tj) {
            int cg  = c0 + wn * 64 + tj * 16 + quad * 4;
            int rem = cg - jq * PC;
            int h   = rem / PHD;
            int ds  = rem - h * PHD;          // multiple of 4
            float4v bv = *(const float4v*)&bias[cg];
#pragma unroll
            for (int ti = 0; ti < 4; ++ti) {
                int m = m0 + wm * 64 + ti * 16 + lrow;
                int b = m >> 10, n = m & 1023;
                size_t chunk = ((size_t)(b * PH + h) * 16 + (n >> 6)) * CHUNK_HALVES;
                half4_t hv;
#pragma unroll
                for (int r = 0; r < 4; ++r)
                    hv[r] = (_Float16)((acc[ti][tj][r] + bv[r]) * mulv);
                if (jq == 0)
                    *(half4_t*)&dstp[chunk + (ds >> 3) * 512 + (n & 63) * 8 + (ds & 7)] = hv;
                else
                    *(half4_t*)&dstp[chunk + ((n & 63) >> 5) * SUB_HALVES
                                     + (ds >> 3) * 256 + (n & 31) * 8 + (ds & 7)] = hv;
            }
        }
    } else {
#pragma unroll
        for (int tj = 0; tj < 4; ++tj) {
            int c   = c0 + wn * 64 + tj * 16 + lrow;
            int rem = c - 2 * PC;
            int h   = rem / PHD;
            int d   = rem - h * PHD;
            float bv = bias[c];
#pragma unroll
            for (int ti = 0; ti < 4; ++ti) {
                int mg = m0 + wm * 64 + ti * 16 + quad * 4;
                int b = mg >> 10, n = mg & 1023;
                size_t chunk = ((size_t)(b * PH + h) * 16 + (n >> 6)) * CHUNK_HALVES;
                half4_t hv;
#pragma unroll
                for (int r = 0; r < 4; ++r)
                    hv[r] = (_Float16)(acc[ti][tj][r] + bv);
                *(half4_t*)&vth[chunk + ((n & 63) >> 3) * 768 + d * 8 + (n & 7)] = hv;
            }
        }
    }
}

// ---------------------------------------------------------------------------
// Stage one 32-row K/V sub-chunk (3072 + 3072 halves) via 12 wave-uniform
// global_load_lds segments of 512 halves (seg = i*4 + wave).
// ---------------------------------------------------------------------------
__device__ __forceinline__ void stage_sub(
    const _Float16* kc, const _Float16* vc,
    _Float16* Ks, _Float16* Vs, int w, int lane)
{
#pragma unroll
    for (int i = 0; i < 3; ++i) {
        int seg = i * 4 + w;
        const _Float16* src = (seg < 6) ? kc + seg * 512 : vc + (seg - 6) * 512;
        _Float16*       dst = (seg < 6) ? Ks + seg * 512 : Vs + (seg - 6) * 512;
        load16_lds(src + lane * 8, dst + lane * 8);
    }
}

// ---------------------------------------------------------------------------
// One 32-key transposed flash-attention sub-step (base-2 softmax):
//   S^T = K Q^T (2 ct of 16 kidx); lane-local softmax (2 shfls);
//   P -> B-layout (2 half4 writes); O^T += V^T P^T (1 k-step, 5 ct).
// ---------------------------------------------------------------------------
__device__ __forceinline__ void attn_sub(
    const half8_t qf[3], const _Float16* Ks, const _Float16* Vs, _Float16* Pw,
    float4v O[5], float& m_run, float& l_run, int ln, int quad)
{
    float4v accS[2];
#pragma unroll
    for (int ct = 0; ct < 2; ++ct) accS[ct] = (float4v){0.f, 0.f, 0.f, 0.f};
#pragma unroll
    for (int ks = 0; ks < 3; ++ks) {
#pragma unroll
        for (int ct = 0; ct < 2; ++ct) {
            half8_t kf = *(const half8_t*)&Ks[(((ks * 4 + quad) * 32) + ct * 16 + ln) * 8];
            accS[ct] = __builtin_amdgcn_mfma_f32_16x16x32_f16(kf, qf[ks], accS[ct], 0, 0, 0);
        }
    }

    float mx = fmaxf(fmaxf(fmaxf(accS[0][0], accS[0][1]), fmaxf(accS[0][2], accS[0][3])),
                     fmaxf(fmaxf(accS[1][0], accS[1][1]), fmaxf(accS[1][2], accS[1][3])));
    mx = fmaxf(mx, __shfl_xor(mx, 16));
    mx = fmaxf(mx, __shfl_xor(mx, 32));
    float m_new = fmaxf(m_run, mx);
    float alpha = exp2f(m_run - m_new);
    m_run = m_new;

    float lsum = 0.f;
    const int pbase = (quad >> 1) * 128 + ln * 8 + (quad & 1) * 4;
#pragma unroll
    for (int ct = 0; ct < 2; ++ct) {
        half4_t pk;
#pragma unroll
        for (int r = 0; r < 4; ++r) {
            float p = exp2f(accS[ct][r] - m_new);
            lsum += p;
            pk[r] = (_Float16)p;
        }
        *(half4_t*)&Pw[pbase + ct * 256] = pk;
    }
    lsum += __shfl_xor(lsum, 16);
    lsum += __shfl_xor(lsum, 32);
    l_run = l_run * alpha + lsum;

#pragma unroll
    for (int ct = 0; ct < 5; ++ct) O[ct] *= alpha;

    half8_t pf = *(const half8_t*)&Pw[quad * 128 + ln * 8];
#pragma unroll
    for (int ct = 0; ct < 5; ++ct) {
        half8_t vf = *(const half8_t*)&Vs[(quad * 96 + ct * 16 + ln) * 8];
        O[ct] = __builtin_amdgcn_mfma_f32_16x16x32_f16(vf, pf, O[ct], 0, 0, 0);
    }
}

// ---------------------------------------------------------------------------
// Fused dual-pass flash attention. 256 threads = 4 waves x 16 Q-rows.
// 32-row K/V sub-chunks, double-buffered: DMA for sub s+1 issues before
// compute of sub s, so the barrier drain overlaps a full compute phase.
// ~29 KB LDS -> 5 blocks/CU. Q in registers. XCD-affinity swizzle.
// ---------------------------------------------------------------------------
__global__ __launch_bounds__(256) void attn_fused(
    const _Float16* __restrict__ qh, const _Float16* __restrict__ kh,
    const _Float16* __restrict__ vth,
    const _Float16* __restrict__ ekh, const _Float16* __restrict__ evth,
    _Float16* __restrict__ xouth, float* __restrict__ loss_out)
{
    const int t = threadIdx.x;
    const int lane = t & 63;
    const int w = t >> 6;
    const int ln = lane & 15;
    const int quad = lane >> 4;

    const int lid  = blockIdx.x;             // 1024 blocks
    const int bh   = (lid & 7) * 8 + ((lid >> 3) >> 4);
    const int nblk = (lid >> 3) & 15;

    __shared__ _Float16 Ks[2][SUB_HALVES];
    __shared__ _Float16 Vs[2][SUB_HALVES];
    __shared__ _Float16 Ps[2048];            // 4 waves x 512
    __shared__ float red[256];

    _Float16* Pw = Ps + w * 512;

    // Q fragments straight to registers (wave-private rows w*16+ln)
    const _Float16* qc = qh + ((size_t)bh * 16 + nblk) * CHUNK_HALVES;
    half8_t qf[3];
#pragma unroll
    for (int ks = 0; ks < 3; ++ks)
        qf[ks] = *(const half8_t*)&qc[(((ks * 4 + quad) * 64) + w * 16 + ln) * 8];

    const _Float16* kbo = kh   + (size_t)bh * HEAD_HALVES;
    const _Float16* vbo = vth  + (size_t)bh * HEAD_HALVES;
    const _Float16* kbe = ekh  + (size_t)bh * HEAD_HALVES;
    const _Float16* vbe = evth + (size_t)bh * HEAD_HALVES;

    float4v Oo[5], Oe[5];
#pragma unroll
    for (int ct = 0; ct < 5; ++ct) {
        Oo[ct] = (float4v){0.f, 0.f, 0.f, 0.f};
        Oe[ct] = (float4v){0.f, 0.f, 0.f, 0.f};
    }
    float m_o = -1e30f, l_o = 0.f;
    float m_e = -1e30f, l_e = 0.f;

    // prologue: own sub 0 -> buf 0
    stage_sub(kbo, vbo, Ks[0], Vs[0], w, lane);
    __syncthreads();

    // pass 0: own K/V, 32 sub-steps
    for (int s = 0; s < 32; ++s) {
        const int cur = s & 1, nxt = cur ^ 1;
        if (s < 31)
            stage_sub(kbo + (s + 1) * SUB_HALVES, vbo + (s + 1) * SUB_HALVES,
                      Ks[nxt], Vs[nxt], w, lane);
        else
            stage_sub(kbe, vbe, Ks[nxt], Vs[nxt], w, lane);  // enc sub 0
        attn_sub(qf, Ks[cur], Vs[cur], Pw, Oo, m_o, l_o, ln, quad);
        __syncthreads();   // all waves done with cur; nxt DMA drained
    }
    // pass 1: encoder K/V (sub 0 already in buf 0)
    for (int s = 0; s < 32; ++s) {
        const int cur = s & 1, nxt = cur ^ 1;
        if (s < 31)
            stage_sub(kbe + (s + 1) * SUB_HALVES, vbe + (s + 1) * SUB_HALVES,
                      Ks[nxt], Vs[nxt], w, lane);
        attn_sub(qf, Ks[cur], Vs[cur], Pw, Oe, m_e, l_e, ln, quad);
        __syncthreads();
    }

    const float inv_o = 1.0f / l_o;
    const float inv_e = 1.0f / l_e;

    const int b = bh >> 4, h = bh & 15;
    const int nrow = nblk * 64 + w * 16 + ln;   // this lane's Q-row

    float lacc = 0.f;
    const size_t rowbase = (size_t)(b * PN + nrow) * PC + h * PHD;
#pragma unroll
    for (int ct = 0; ct < 5; ++ct) {
        int d0 = ct * 16 + quad * 4;
        if (d0 < PHD) {                  // ct=4: only quads 0,1 valid
            half4_t oh;
#pragma unroll
            for (int r = 0; r < 4; ++r) {
                float own = Oo[ct][r] * inv_o;
                oh[r] = (_Float16)own;
                float df = own - Oe[ct][r] * inv_e;
                lacc += df * df;
            }
            *(half4_t*)&xouth[rowbase + d0] = oh;   // 8B aligned
        }
    }

    red[t] = lacc;
    __syncthreads();
    for (int off = 128; off > 0; off >>= 1) {
        if (t < off) red[t] += red[t + off];
        __syncthreads();
    }
    if (t == 0) atomicAdd(loss_out, red[0] * (1.0f / (float)OUT_ELEMS));
}

// ---------------------------------------------------------------------------
extern "C" void kernel_launch(void* const* d_in, const int* in_sizes, int n_in,
                              void* d_out, int out_size, void* d_ws, size_t ws_size,
                              hipStream_t stream)
{
    const float* x      = (const float*)d_in[0];
    const float* enc_k  = (const float*)d_in[1];
    const float* enc_v  = (const float*)d_in[2];
    const float* qkv_w  = (const float*)d_in[3];
    const float* qkv_b  = (const float*)d_in[4];
    const float* proj_w = (const float*)d_in[5];
    const float* proj_b = (const float*)d_in[6];

    float* out = (float*)d_out;

    _Float16* x_h     = (_Float16*)d_ws;
    _Float16* qkvw_h  = x_h + OUT_ELEMS;
    _Float16* projw_h = qkvw_h + (size_t)QKV_COLS * PC;
    _Float16* xout_h  = projw_h + (size_t)PC * PC;
    _Float16* q_h     = xout_h + OUT_ELEMS;
    _Float16* k_h     = q_h  + BUF_HALVES;
    _Float16* vt_h    = k_h  + BUF_HALVES;
    _Float16* ek_h    = vt_h + BUF_HALVES;
    _Float16* evt_h   = ek_h + BUF_HALVES;

    // 0. zero loss slot
    hipMemsetAsync(out + OUT_ELEMS, 0, sizeof(float), stream);

    // 1. fused prep (conversions + q-pad zero + enc convert)
    prep<<<6688, 256, 0, stream>>>(x, qkv_w, proj_w, enc_k, enc_v,
                                   x_h, qkvw_h, projw_h, q_h, ek_h, evt_h);

    // 2. QKV projection -> blocked f16 q/k/vt (q pre-scaled by QSCALE)
    gemm_mfma<0><<<(QKV_COLS / 128) * ((PB * PN) / 128), 256, 0, stream>>>(
        x_h, qkvw_h, qkv_b, q_h, k_h, vt_h, nullptr, QKV_COLS / 128);

    // 3. Fused own+enc attention -> xout_h + loss into out[OUT_ELEMS]
    attn_fused<<<16 * BH, 256, 0, stream>>>(
        q_h, k_h, vt_h, ek_h, evt_h, xout_h, out + OUT_ELEMS);

    // 4. Output projection (transposed, float4 stores)
    gemm_mfma<1><<<(PC / 128) * ((PB * PN) / 128), 256, 0, stream>>>(
        xout_h, projw_h, proj_b, nullptr, nullptr, nullptr, out, PC / 128);
}